// Round 4
// baseline (367.143 us; speedup 1.0000x reference)
//
#include <hip/hip_runtime.h>
#include <hip/hip_bf16.h>
#include <stdint.h>
#include <stddef.h>

// out[M,N] = X[M,K] @ sign(W[N,K])^T + bias[N];  M=N=K=4096, fp32 in/out.
// Single fused kernel: fp32 loads -> convert/binarize in registers ->
// swizzled LDS -> 16x16x32 bf16 MFMA. Register-staged prefetch keeps the
// next tile's global loads in flight across the barrier (global->VGPR loads
// are private, so s_barrier only drains lgkmcnt, not vmcnt -- unlike
// global_load_lds, whose vmcnt(0) drain caused the R3 150us plateau).
#define M_DIM 4096
#define N_DIM 4096
#define K_DIM 4096
#define BM 128
#define BN 128
#define BK 64
#define NKT (K_DIM / BK)   // 64
#define K4  (K_DIM / 4)    // 1024 float4 per row

typedef __bf16 bf16;
typedef __attribute__((ext_vector_type(8))) __bf16 bf16x8;
typedef __attribute__((ext_vector_type(4))) float f32x4;

// RNE fp32->bf16 pair, packed into one dword (lo = a, hi = b).
__device__ __forceinline__ uint32_t pack_bf16(float a, float b) {
    uint16_t ua = __builtin_bit_cast(uint16_t, (bf16)a);
    uint16_t ub = __builtin_bit_cast(uint16_t, (bf16)b);
    return (uint32_t)ua | ((uint32_t)ub << 16);
}
// sign(a),sign(b) as bf16 pair: +/-1.0 = 0x3F80 | signbit. Exact for all
// nonzero inputs; exact-0.0 has measure zero for random-normal weights.
__device__ __forceinline__ uint32_t sign_pack(float a, float b) {
    uint32_t ua = __builtin_bit_cast(uint32_t, a);
    uint32_t ub = __builtin_bit_cast(uint32_t, b);
    return 0x3F803F80u | ((ua >> 16) & 0x8000u) | (ub & 0x80000000u);
}

// 512 threads = 8 waves in a 2x4 grid; each wave owns 64x32 (4x2 MFMAs of
// 16x16x32). 512 threads keeps per-thread staging to 8 float4 in flight and
// per-wave acc to 32 VGPRs (target ~4 waves/SIMD).
__global__ __launch_bounds__(512) void gemm_fused_kernel(
    const float* __restrict__ X, const float* __restrict__ W,
    const float* __restrict__ bias, float* __restrict__ C)
{
    // LDS layout (R3-proven, 0 conflicts): row r (64 bf16 = 8 granules of
    // 16 B); granule g stored at slot s = g ^ (r&7).
    __shared__ __align__(16) bf16 As[BM * BK];   // 16 KB
    __shared__ __align__(16) bf16 Bs[BN * BK];   // 16 KB

    const int tid  = threadIdx.x;
    const int lane = tid & 63;
    const int wave = tid >> 6;
    const int wm   = wave & 1;    // 2 row-blocks of 64
    const int wn   = wave >> 1;   // 4 col-blocks of 32

    const int tileM = blockIdx.y * BM;
    const int tileN = blockIdx.x * BN;

    // --- staging thread map: pass p in 0..3, row = p*32 + (tid>>4),
    // float4-col c4 = tid&15 (elems c4*4..+3 of the 64-elem row).
    const int rT = tid >> 4;          // 0..31
    const int c4 = tid & 15;
    // granule g = c4>>1, half h = c4&1, row&7 = rT&7 (32 & 96 are mult of 8)
    const int sw = (c4 >> 1) ^ (rT & 7);
    const uint32_t ldsOff = (uint32_t)rT * 128 + (uint32_t)sw * 16 + (uint32_t)(c4 & 1) * 8;
    char* ldsA = (char*)As + ldsOff;  // + p*4096 per pass
    char* ldsB = (char*)Bs + ldsOff;

    int offX[4], offW[4];             // float4 offsets, + kt*16 per iter
#pragma unroll
    for (int p = 0; p < 4; ++p) {
        offX[p] = (tileM + p * 32 + rT) * K4 + c4;
        offW[p] = (tileN + p * 32 + rT) * K4 + c4;
    }
    const float4* X4 = (const float4*)X;
    const float4* W4 = (const float4*)W;

    f32x4 acc[4][2];
#pragma unroll
    for (int i = 0; i < 4; ++i)
#pragma unroll
        for (int j = 0; j < 2; ++j)
            acc[i][j] = (f32x4){0.f, 0.f, 0.f, 0.f};

    // Fragment addressing (R3-proven): lane = qf*16 + l15; k-granule
    // g = kk*4 + qf lives at slot s = g ^ (l15&7) of row base + l15.
    const int l15 = lane & 15;
    const int qf  = lane >> 4;
    const int fragRowA = wm * 64 + l15;
    const int fragRowB = wn * 32 + l15;

    // Prologue: tile 0 loads into registers.
    float4 ldA[4], ldB[4];
#pragma unroll
    for (int p = 0; p < 4; ++p) { ldA[p] = X4[offX[p]]; ldB[p] = W4[offW[p]]; }

    for (int kt = 0; kt < NKT; ++kt) {
        // Pack tile kt (vmcnt wait for its loads lands HERE -- after the
        // previous iteration's MFMA block).
        uint2 stA[4], stB[4];
#pragma unroll
        for (int p = 0; p < 4; ++p) {
            stA[p].x = pack_bf16(ldA[p].x, ldA[p].y);
            stA[p].y = pack_bf16(ldA[p].z, ldA[p].w);
            stB[p].x = sign_pack(ldB[p].x, ldB[p].y);
            stB[p].y = sign_pack(ldB[p].z, ldB[p].w);
        }
#pragma unroll
        for (int p = 0; p < 4; ++p) {
            *(uint2*)(ldsA + p * 4096) = stA[p];
            *(uint2*)(ldsB + p * 4096) = stB[p];
        }
        __syncthreads();   // lgkmcnt drain only: tile kt visible

        // Prefetch tile kt+1 into registers; stays in flight across MFMA.
        if (kt + 1 < NKT) {
            const int ko = (kt + 1) * 16;
#pragma unroll
            for (int p = 0; p < 4; ++p) {
                ldA[p] = X4[offX[p] + ko];
                ldB[p] = W4[offW[p] + ko];
            }
        }

        // Compute tile kt.
#pragma unroll
        for (int kk = 0; kk < 2; ++kk) {
            const int s = (kk * 4 + qf) ^ (l15 & 7);
            bf16x8 af[4], bfr[2];
#pragma unroll
            for (int i = 0; i < 4; ++i)
                af[i] = *(const bf16x8*)&As[(fragRowA + i * 16) * BK + s * 8];
#pragma unroll
            for (int j = 0; j < 2; ++j)
                bfr[j] = *(const bf16x8*)&Bs[(fragRowB + j * 16) * BK + s * 8];
#pragma unroll
            for (int i = 0; i < 4; ++i)
#pragma unroll
                for (int j = 0; j < 2; ++j)
                    acc[i][j] = __builtin_amdgcn_mfma_f32_16x16x32_bf16(af[i], bfr[j], acc[i][j], 0, 0, 0);
        }
        __syncthreads();   // frag reads done before next iter's ds_write
    }

    // --- epilogue: C/D layout col = lane&15, row = (lane>>4)*4 + reg ------
#pragma unroll
    for (int j = 0; j < 2; ++j) {
        const int col = tileN + wn * 32 + j * 16 + l15;
        const float bv = bias[col];
#pragma unroll
        for (int i = 0; i < 4; ++i) {
            const int row0 = tileM + wm * 64 + i * 16 + (qf << 2);
#pragma unroll
            for (int rr = 0; rr < 4; ++rr) {
                C[(size_t)(row0 + rr) * N_DIM + col] = acc[i][j][rr] + bv;
            }
        }
    }
}

// ---------------------------------------------------------------------------
extern "C" void kernel_launch(void* const* d_in, const int* in_sizes, int n_in,
                              void* d_out, int out_size, void* d_ws, size_t ws_size,
                              hipStream_t stream) {
    const float* x    = (const float*)d_in[0];  // [M,K]
    const float* w    = (const float*)d_in[1];  // [N,K]
    const float* bias = (const float*)d_in[2];  // [N]
    float* out        = (float*)d_out;          // [M,N]

    dim3 grid(N_DIM / BN, M_DIM / BM);          // 32 x 32
    gemm_fused_kernel<<<grid, 512, 0, stream>>>(x, w, bias, out);
}